// Round 6
// baseline (173.242 us; speedup 1.0000x reference)
//
#include <hip/hip_runtime.h>
#include <hip/hip_bf16.h>

// out[m,n] = sum_k x[m,k] * W[1023-n,k] + b[1023-n]
// M=32768, N=256, K=512; fp32 in/out; bf16 MFMA.
// Barrier-free, LDS-free streaming GEMM (R4 geometry + R5 pinned schedule):
//  - prepass: W_sel -> bf16 Bmat[256][512] n-major in d_ws (256 KiB, L2/L1-resident)
//  - gemm: A direct from x in frag layout (16 rows x 128B lines, perfectly coalesced),
//    3-deep pinned A-prefetch, 2-deep pinned B-prefetch, sched_barrier(0) fences.

#define M_TOT 32768
#define K_TOT 512
#define N_TOT 256
#define W_LD  1024

#define NTH 256              /* 4 waves */
#define BM  32               /* grid 1024 = 4 blocks/CU */

typedef __bf16 bf16x8 __attribute__((ext_vector_type(8)));
typedef float  f32x4  __attribute__((ext_vector_type(4)));

static __device__ __forceinline__ bf16x8 cvt8(f32x4 a, f32x4 b) {
    bf16x8 r;
    r[0] = (__bf16)a[0]; r[1] = (__bf16)a[1]; r[2] = (__bf16)a[2]; r[3] = (__bf16)a[3];
    r[4] = (__bf16)b[0]; r[5] = (__bf16)b[1]; r[6] = (__bf16)b[2]; r[7] = (__bf16)b[3];
    return r;
}

// ---- prepass: Bmat[n][k] = bf16(W[1023-n][k]) ----
__global__ __launch_bounds__(256)
void ng_prep(const float* __restrict__ W, __bf16* __restrict__ Bm)
{
    const int id = blockIdx.x * 256 + threadIdx.x;   // 16384 units: n(256) x kg(64)
    const int n  = id >> 6;
    const int kg = id & 63;
    const float* src = W + (long)(1023 - n) * W_LD + kg * 8;
    f32x4 a = *(const f32x4*)src;
    f32x4 b = *(const f32x4*)(src + 4);
    *(bf16x8*)(Bm + n * K_TOT + kg * 8) = cvt8(a, b);
}

__global__ __launch_bounds__(NTH, 4)
void ng_gemm(const float* __restrict__ x, const __bf16* __restrict__ Bm,
             const float* __restrict__ bias, float* __restrict__ out)
{
    const int lane = threadIdx.x & 63;
    const int wcol = threadIdx.x >> 6;      // 0..3 : 64 output cols each
    const long mBase = (long)blockIdx.x * BM;

    const int r16 = lane & 15;              // row within frag
    const int ko  = lane >> 4;              // k-octet 0..3

    // A: lane reads x[mBase + mi*16 + r16][S*32 + ko*8 .. +7]  (imm offset = S*128B)
    const float* pa0 = x + (mBase + r16) * K_TOT + ko * 8;
    const float* pa1 = pa0 + 16 * K_TOT;
    // B: lane reads Bmat[wcol*64 + ni*16 + r16][S*32 + ko*8 .. +7] (imm = S*64B)
    const __bf16* pb0 = Bm + (wcol * 64 + r16) * K_TOT + ko * 8;
    const __bf16* pb1 = pb0 + 16 * K_TOT;
    const __bf16* pb2 = pb0 + 32 * K_TOT;
    const __bf16* pb3 = pb0 + 48 * K_TOT;

    f32x4 acc[2][4];
#pragma unroll
    for (int mi = 0; mi < 2; ++mi)
#pragma unroll
        for (int ni = 0; ni < 4; ++ni)
            acc[mi][ni] = (f32x4){0.f, 0.f, 0.f, 0.f};

    f32x4  As[3][4];    // 3-deep rotating A prefetch (all indices compile-time)
    bf16x8 Bs[2][4];    // 2-deep rotating B prefetch

#define LOADA(slot_, S_) do {                                   \
        As[slot_][0] = *(const f32x4*)(pa0 + (S_) * 32);        \
        As[slot_][1] = *(const f32x4*)(pa0 + (S_) * 32 + 4);    \
        As[slot_][2] = *(const f32x4*)(pa1 + (S_) * 32);        \
        As[slot_][3] = *(const f32x4*)(pa1 + (S_) * 32 + 4);    \
    } while (0)

#define LOADB(slot_, S_) do {                                   \
        Bs[slot_][0] = *(const bf16x8*)(pb0 + (S_) * 32);       \
        Bs[slot_][1] = *(const bf16x8*)(pb1 + (S_) * 32);       \
        Bs[slot_][2] = *(const bf16x8*)(pb2 + (S_) * 32);       \
        Bs[slot_][3] = *(const bf16x8*)(pb3 + (S_) * 32);       \
    } while (0)

// step S: cvt A(S) [waits its loads], refill A slot with S+3, MFMA vs B(S), refill B with S+2
#define STEP(S_) do {                                                         \
        bf16x8 a0_ = cvt8(As[(S_) % 3][0], As[(S_) % 3][1]);                  \
        bf16x8 a1_ = cvt8(As[(S_) % 3][2], As[(S_) % 3][3]);                  \
        __builtin_amdgcn_sched_barrier(0);                                    \
        if ((S_) + 3 < 16) LOADA((S_) % 3, (S_) + 3);                         \
        __builtin_amdgcn_sched_barrier(0);                                    \
        __builtin_amdgcn_s_setprio(1);                                        \
        _Pragma("unroll")                                                     \
        for (int ni_ = 0; ni_ < 4; ++ni_) {                                   \
            acc[0][ni_] = __builtin_amdgcn_mfma_f32_16x16x32_bf16(            \
                a0_, Bs[(S_) & 1][ni_], acc[0][ni_], 0, 0, 0);                \
            acc[1][ni_] = __builtin_amdgcn_mfma_f32_16x16x32_bf16(            \
                a1_, Bs[(S_) & 1][ni_], acc[1][ni_], 0, 0, 0);                \
        }                                                                     \
        __builtin_amdgcn_s_setprio(0);                                        \
        __builtin_amdgcn_sched_barrier(0);                                    \
        if ((S_) + 2 < 16) LOADB((S_) & 1, (S_) + 2);                         \
        __builtin_amdgcn_sched_barrier(0);                                    \
    } while (0)

    // prologue: fill the pipeline (20 loads in flight)
    LOADA(0, 0); LOADA(1, 1); LOADA(2, 2);
    LOADB(0, 0); LOADB(1, 1);

    STEP(0);  STEP(1);  STEP(2);  STEP(3);
    STEP(4);  STEP(5);  STEP(6);  STEP(7);
    STEP(8);  STEP(9);  STEP(10); STEP(11);
    STEP(12); STEP(13); STEP(14); STEP(15);

    // ---- epilogue: C/D layout col=lane&15, row=(lane>>4)*4+i ; reversed bias ----
    const int cRow = (lane >> 4) * 4;
    const int cCol = wcol * 64 + (lane & 15);
#pragma unroll
    for (int ni = 0; ni < 4; ++ni) {
        const int gn = cCol + ni * 16;
        const float bv = bias[1023 - gn];
#pragma unroll
        for (int mi = 0; mi < 2; ++mi) {
            float* dst = out + (mBase + cRow + mi * 16) * (long)N_TOT + gn;
#pragma unroll
            for (int i = 0; i < 4; ++i)
                dst[(long)i * N_TOT] = acc[mi][ni][i] + bv;
        }
    }
#undef LOADA
#undef LOADB
#undef STEP
}

extern "C" void kernel_launch(void* const* d_in, const int* in_sizes, int n_in,
                              void* d_out, int out_size, void* d_ws, size_t ws_size,
                              hipStream_t stream) {
    const float* x = (const float*)d_in[0];   // 32768 x 512 fp32
    const float* W = (const float*)d_in[1];   // 1024 x 1024 fp32
    const float* b = (const float*)d_in[2];   // 1024 fp32
    float* out = (float*)d_out;               // 32768 x 256 fp32
    __bf16* Bm = (__bf16*)d_ws;               // 256 KiB bf16 W image

    ng_prep<<<dim3(64), dim3(256), 0, stream>>>(W, Bm);
    ng_gemm<<<dim3(M_TOT / BM), dim3(NTH), 0, stream>>>(x, Bm, b, out);
}

// Round 7
// 152.901 us; speedup vs baseline: 1.1330x; 1.1330x over previous
//
#include <hip/hip_runtime.h>
#include <hip/hip_bf16.h>

// out[m,n] = sum_k x[m,k] * W[1023-n,k] + b[1023-n]
// M=32768, N=256, K=512; fp32 in/out; bf16 MFMA.
// Barrier-free, LDS-free streaming GEMM, pinned 3-deep A / 2-deep B prefetch.
// R7 = R6 with launch_bounds(256,3): VGPR cap 170 (R6's cap of 128 spilled the
// pipeline arrays to scratch -> WRITE_SIZE 33->86 MB, the whole regression).

#define M_TOT 32768
#define K_TOT 512
#define N_TOT 256
#define W_LD  1024

#define NTH 256              /* 4 waves */
#define BM  32               /* grid 1024 */

typedef __bf16 bf16x8 __attribute__((ext_vector_type(8)));
typedef float  f32x4  __attribute__((ext_vector_type(4)));

static __device__ __forceinline__ bf16x8 cvt8(f32x4 a, f32x4 b) {
    bf16x8 r;
    r[0] = (__bf16)a[0]; r[1] = (__bf16)a[1]; r[2] = (__bf16)a[2]; r[3] = (__bf16)a[3];
    r[4] = (__bf16)b[0]; r[5] = (__bf16)b[1]; r[6] = (__bf16)b[2]; r[7] = (__bf16)b[3];
    return r;
}

// ---- prepass: Bmat[n][k] = bf16(W[1023-n][k]) ----
__global__ __launch_bounds__(256)
void ng_prep(const float* __restrict__ W, __bf16* __restrict__ Bm)
{
    const int id = blockIdx.x * 256 + threadIdx.x;   // 16384 units: n(256) x kg(64)
    const int n  = id >> 6;
    const int kg = id & 63;
    const float* src = W + (long)(1023 - n) * W_LD + kg * 8;
    f32x4 a = *(const f32x4*)src;
    f32x4 b = *(const f32x4*)(src + 4);
    *(bf16x8*)(Bm + n * K_TOT + kg * 8) = cvt8(a, b);
}

__global__ __launch_bounds__(NTH, 3)
void ng_gemm(const float* __restrict__ x, const __bf16* __restrict__ Bm,
             const float* __restrict__ bias, float* __restrict__ out)
{
    const int lane = threadIdx.x & 63;
    const int wcol = threadIdx.x >> 6;      // 0..3 : 64 output cols each
    const long mBase = (long)blockIdx.x * BM;

    const int r16 = lane & 15;              // row within frag
    const int ko  = lane >> 4;              // k-octet 0..3

    // A: lane reads x[mBase + mi*16 + r16][S*32 + ko*8 .. +7]  (imm offset = S*128B)
    const float* pa0 = x + (mBase + r16) * K_TOT + ko * 8;
    const float* pa1 = pa0 + 16 * K_TOT;
    // B: lane reads Bmat[wcol*64 + ni*16 + r16][S*32 + ko*8 .. +7] (imm = S*64B)
    const __bf16* pb0 = Bm + (wcol * 64 + r16) * K_TOT + ko * 8;
    const __bf16* pb1 = pb0 + 16 * K_TOT;
    const __bf16* pb2 = pb0 + 32 * K_TOT;
    const __bf16* pb3 = pb0 + 48 * K_TOT;

    f32x4 acc[2][4];
#pragma unroll
    for (int mi = 0; mi < 2; ++mi)
#pragma unroll
        for (int ni = 0; ni < 4; ++ni)
            acc[mi][ni] = (f32x4){0.f, 0.f, 0.f, 0.f};

    f32x4  As[3][4];    // 3-deep rotating A prefetch (all indices compile-time)
    bf16x8 Bs[2][4];    // 2-deep rotating B prefetch

#define LOADA(slot_, S_) do {                                   \
        As[slot_][0] = *(const f32x4*)(pa0 + (S_) * 32);        \
        As[slot_][1] = *(const f32x4*)(pa0 + (S_) * 32 + 4);    \
        As[slot_][2] = *(const f32x4*)(pa1 + (S_) * 32);        \
        As[slot_][3] = *(const f32x4*)(pa1 + (S_) * 32 + 4);    \
    } while (0)

#define LOADB(slot_, S_) do {                                   \
        Bs[slot_][0] = *(const bf16x8*)(pb0 + (S_) * 32);       \
        Bs[slot_][1] = *(const bf16x8*)(pb1 + (S_) * 32);       \
        Bs[slot_][2] = *(const bf16x8*)(pb2 + (S_) * 32);       \
        Bs[slot_][3] = *(const bf16x8*)(pb3 + (S_) * 32);       \
    } while (0)

// step S: cvt A(S) [waits its loads], refill A slot with S+3, MFMA vs B(S), refill B with S+2
#define STEP(S_) do {                                                         \
        bf16x8 a0_ = cvt8(As[(S_) % 3][0], As[(S_) % 3][1]);                  \
        bf16x8 a1_ = cvt8(As[(S_) % 3][2], As[(S_) % 3][3]);                  \
        __builtin_amdgcn_sched_barrier(0);                                    \
        if ((S_) + 3 < 16) LOADA((S_) % 3, (S_) + 3);                         \
        __builtin_amdgcn_sched_barrier(0);                                    \
        __builtin_amdgcn_s_setprio(1);                                        \
        _Pragma("unroll")                                                     \
        for (int ni_ = 0; ni_ < 4; ++ni_) {                                   \
            acc[0][ni_] = __builtin_amdgcn_mfma_f32_16x16x32_bf16(            \
                a0_, Bs[(S_) & 1][ni_], acc[0][ni_], 0, 0, 0);                \
            acc[1][ni_] = __builtin_amdgcn_mfma_f32_16x16x32_bf16(            \
                a1_, Bs[(S_) & 1][ni_], acc[1][ni_], 0, 0, 0);                \
        }                                                                     \
        __builtin_amdgcn_s_setprio(0);                                        \
        __builtin_amdgcn_sched_barrier(0);                                    \
        if ((S_) + 2 < 16) LOADB((S_) & 1, (S_) + 2);                         \
        __builtin_amdgcn_sched_barrier(0);                                    \
    } while (0)

    // prologue: fill the pipeline (20 loads in flight)
    LOADA(0, 0); LOADA(1, 1); LOADA(2, 2);
    LOADB(0, 0); LOADB(1, 1);

    STEP(0);  STEP(1);  STEP(2);  STEP(3);
    STEP(4);  STEP(5);  STEP(6);  STEP(7);
    STEP(8);  STEP(9);  STEP(10); STEP(11);
    STEP(12); STEP(13); STEP(14); STEP(15);

    // ---- epilogue: C/D layout col=lane&15, row=(lane>>4)*4+i ; reversed bias ----
    const int cRow = (lane >> 4) * 4;
    const int cCol = wcol * 64 + (lane & 15);
#pragma unroll
    for (int ni = 0; ni < 4; ++ni) {
        const int gn = cCol + ni * 16;
        const float bv = bias[1023 - gn];
#pragma unroll
        for (int mi = 0; mi < 2; ++mi) {
            float* dst = out + (mBase + cRow + mi * 16) * (long)N_TOT + gn;
#pragma unroll
            for (int i = 0; i < 4; ++i)
                dst[(long)i * N_TOT] = acc[mi][ni][i] + bv;
        }
    }
#undef LOADA
#undef LOADB
#undef STEP
}

extern "C" void kernel_launch(void* const* d_in, const int* in_sizes, int n_in,
                              void* d_out, int out_size, void* d_ws, size_t ws_size,
                              hipStream_t stream) {
    const float* x = (const float*)d_in[0];   // 32768 x 512 fp32
    const float* W = (const float*)d_in[1];   // 1024 x 1024 fp32
    const float* b = (const float*)d_in[2];   // 1024 fp32
    float* out = (float*)d_out;               // 32768 x 256 fp32
    __bf16* Bm = (__bf16*)d_ws;               // 256 KiB bf16 W image

    ng_prep<<<dim3(64), dim3(256), 0, stream>>>(W, Bm);
    ng_gemm<<<dim3(M_TOT / BM), dim3(NTH), 0, stream>>>(x, Bm, b, out);
}